// Round 1
// baseline (1327.073 us; speedup 1.0000x reference)
//
#include <hip/hip_runtime.h>
#include <math.h>
#include <float.h>

#define EMB     512
#define NROWS   8192
#define NITEMS  4096
#define NSPLIT  8
#define BM      64
#define BN      128
#define BK      32
#define TM      4
#define TN      8
#define COLS_PER_SPLIT (NROWS / NSPLIT)   // 1024
#define NTILES  (COLS_PER_SPLIT / BN)     // 8

// ---------------- Phase A: per-row inverse norms ----------------
__global__ void norm_kernel(const float* __restrict__ E, float* __restrict__ invn) {
    int row  = blockIdx.x * 4 + (threadIdx.x >> 6);   // 4 waves per block, 1 row per wave
    int lane = threadIdx.x & 63;
    const float* p = E + (size_t)row * EMB;
    float s = 0.f;
#pragma unroll
    for (int k = 0; k < EMB / 64; ++k) {
        float v = p[lane + k * 64];
        s = fmaf(v, v, s);
    }
#pragma unroll
    for (int off = 32; off > 0; off >>= 1) s += __shfl_down(s, off);
    if (lane == 0) invn[row] = 1.0f / sqrtf(s);
}

// ---------------- Phase B: tiled fp32 GEMM + fused per-row top-6 ----------------
__global__ __launch_bounds__(256) void sim_topk_kernel(
    const float* __restrict__ E, const float* __restrict__ invn,
    float* __restrict__ pv, int* __restrict__ pix) {

    __shared__ __align__(16) union {
        struct { float As[BK][BM + 4]; float Bs[BK][BN + 4]; } t;   // 25600 B
        struct { float mv[BM][97]; int mi[BM][97]; } m;             // 49664 B
    } sh;

    const int t     = threadIdx.x;
    const int rb    = blockIdx.x >> 3;       // 128 row-blocks
    const int split = blockIdx.x & 7;        // 8 col splits
    const int row0  = rb * BM;
    const int ty    = t >> 4;                // 0..15, row group
    const int tx    = t & 15;                // 0..15, col group

    // per-thread sorted top-6 per owned row (val desc, idx asc on ties)
    float tv[TM][6];
    int   ti[TM][6];
#pragma unroll
    for (int m = 0; m < TM; ++m)
#pragma unroll
        for (int s = 0; s < 6; ++s) { tv[m][s] = -INFINITY; ti[m][s] = 0x7FFFFFFF; }

    float invA[TM];
#pragma unroll
    for (int m = 0; m < TM; ++m) invA[m] = invn[row0 + ty * TM + m];

    for (int ct = 0; ct < NTILES; ++ct) {
        const int col0 = split * COLS_PER_SPLIT + ct * BN;

        float acc[TM][TN];
#pragma unroll
        for (int m = 0; m < TM; ++m)
#pragma unroll
            for (int n = 0; n < TN; ++n) acc[m][n] = 0.f;

        for (int kk = 0; kk < EMB; kk += BK) {
            __syncthreads();
            // stage A tile 64x32 (transposed into LDS): 512 float4
#pragma unroll
            for (int rep = 0; rep < 2; ++rep) {
                int i  = t + rep * 256;
                int r  = i >> 3;
                int kq = (i & 7) << 2;
                float4 f = *(const float4*)(E + (size_t)(row0 + r) * EMB + kk + kq);
                sh.t.As[kq + 0][r] = f.x;
                sh.t.As[kq + 1][r] = f.y;
                sh.t.As[kq + 2][r] = f.z;
                sh.t.As[kq + 3][r] = f.w;
            }
            // stage B tile 128x32 (transposed): 1024 float4
#pragma unroll
            for (int rep = 0; rep < 4; ++rep) {
                int i  = t + rep * 256;
                int c  = i >> 3;
                int kq = (i & 7) << 2;
                float4 f = *(const float4*)(E + (size_t)(col0 + c) * EMB + kk + kq);
                sh.t.Bs[kq + 0][c] = f.x;
                sh.t.Bs[kq + 1][c] = f.y;
                sh.t.Bs[kq + 2][c] = f.z;
                sh.t.Bs[kq + 3][c] = f.w;
            }
            __syncthreads();
#pragma unroll 8
            for (int k = 0; k < BK; ++k) {
                float4 a  = *(const float4*)&sh.t.As[k][ty * TM];
                float4 b0 = *(const float4*)&sh.t.Bs[k][tx * TN];
                float4 b1 = *(const float4*)&sh.t.Bs[k][tx * TN + 4];
                float ar[TM] = {a.x, a.y, a.z, a.w};
                float br[TN] = {b0.x, b0.y, b0.z, b0.w, b1.x, b1.y, b1.z, b1.w};
#pragma unroll
                for (int m = 0; m < TM; ++m)
#pragma unroll
                    for (int n = 0; n < TN; ++n)
                        acc[m][n] = fmaf(ar[m], br[n], acc[m][n]);
            }
        }

        // scale to cosine sim and update per-thread top-6
        float4 ib0 = *(const float4*)(invn + col0 + tx * TN);
        float4 ib1 = *(const float4*)(invn + col0 + tx * TN + 4);
        float invB[TN] = {ib0.x, ib0.y, ib0.z, ib0.w, ib1.x, ib1.y, ib1.z, ib1.w};
#pragma unroll
        for (int m = 0; m < TM; ++m) {
#pragma unroll
            for (int n = 0; n < TN; ++n) {
                float v = acc[m][n] * invA[m] * invB[n];
                int   j = col0 + tx * TN + n;
                if (v > tv[m][5] || (v == tv[m][5] && j < ti[m][5])) {
                    float cv = v; int ci = j;
#pragma unroll
                    for (int s = 0; s < 6; ++s) {
                        bool better = (cv > tv[m][s]) || (cv == tv[m][s] && ci < ti[m][s]);
                        if (better) {
                            float ft = tv[m][s]; int it = ti[m][s];
                            tv[m][s] = cv; ti[m][s] = ci;
                            cv = ft; ci = it;
                        }
                    }
                }
            }
        }
    }

    // merge 16 thread-lists per row -> per-(row,split) top-6
    __syncthreads();
#pragma unroll
    for (int m = 0; m < TM; ++m)
#pragma unroll
        for (int s = 0; s < 6; ++s) {
            sh.m.mv[ty * TM + m][tx * 6 + s] = tv[m][s];
            sh.m.mi[ty * TM + m][tx * 6 + s] = ti[m][s];
        }
    __syncthreads();
    if (t < BM) {
        const int row = row0 + t;
        size_t base = ((size_t)row * NSPLIT + split) * 6;
        for (int sel = 0; sel < 6; ++sel) {
            float bv = -INFINITY; int bi = 0x7FFFFFFF; int bc = 0;
            for (int c = 0; c < 96; ++c) {
                float v = sh.m.mv[t][c]; int id = sh.m.mi[t][c];
                if (v > bv || (v == bv && id < bi)) { bv = v; bi = id; bc = c; }
            }
            sh.m.mv[t][bc] = -INFINITY; sh.m.mi[t][bc] = 0x7FFFFFFF;
            pv[base + sel]  = bv;
            pix[base + sel] = bi;
        }
    }
}

// ---------------- Phase C: 8-way merge of sorted partials + gather + output ----------------
__global__ void finalize_kernel(
    const float* __restrict__ pv, const int* __restrict__ pix,
    const int* __restrict__ n_users, const int* __restrict__ n_entitys,
    const int* __restrict__ interactions, float* __restrict__ out) {

    int row = blockIdx.x * blockDim.x + threadIdx.x;
    if (row >= NROWS) return;

    int ent = n_entitys[row];
    int p[NSPLIT];
#pragma unroll
    for (int s = 0; s < NSPLIT; ++s) p[s] = 0;

    float sum = 0.f;
    for (int sel = 0; sel < 6; ++sel) {
        float bv = -INFINITY; int bi = 0x7FFFFFFF; int bs = 0;
#pragma unroll
        for (int s = 0; s < NSPLIT; ++s) {
            size_t base = ((size_t)row * NSPLIT + s) * 6 + p[s];
            float v = pv[base]; int id = pix[base];
            if (v > bv || (v == bv && id < bi)) { bv = v; bi = id; bs = s; }
        }
#pragma unroll
        for (int s = 0; s < NSPLIT; ++s) if (s == bs) p[s]++;
        int uid = n_users[bi];
        float memb = (float)interactions[(size_t)uid * NITEMS + ent];
        sum = fmaf(bv, memb, sum);
    }
    out[row] = sum * (1.0f / 6.0f);
}

extern "C" void kernel_launch(void* const* d_in, const int* in_sizes, int n_in,
                              void* d_out, int out_size, void* d_ws, size_t ws_size,
                              hipStream_t stream) {
    const float* E            = (const float*)d_in[0];
    const int*   n_users      = (const int*)d_in[1];
    const int*   n_entitys    = (const int*)d_in[2];
    const int*   interactions = (const int*)d_in[3];
    float*       out          = (float*)d_out;

    // workspace layout: invnorm[8192] | pv[8192*8*6] | pix[8192*8*6]  (~3.2 MB)
    float* invn = (float*)d_ws;
    float* pv   = invn + NROWS;
    int*   pix  = (int*)(pv + (size_t)NROWS * NSPLIT * 6);

    norm_kernel<<<NROWS / 4, 256, 0, stream>>>(E, invn);
    sim_topk_kernel<<<(NROWS / BM) * NSPLIT, 256, 0, stream>>>(E, invn, pv, pix);
    finalize_kernel<<<(NROWS + 255) / 256, 256, 0, stream>>>(pv, pix, n_users, n_entitys,
                                                             interactions, out);
}

// Round 2
// 624.524 us; speedup vs baseline: 2.1249x; 2.1249x over previous
//
#include <hip/hip_runtime.h>
#include <math.h>
#include <float.h>

typedef unsigned short ushort_t;
typedef __attribute__((ext_vector_type(8))) short bf16x8;
typedef __attribute__((ext_vector_type(4))) float f32x4;

#define EMB     512
#define NROWS   8192
#define NITEMS  4096
#define NSPLIT  8
#define COLS_PER_SPLIT (NROWS / NSPLIT)   // 1024
#define NTILES  (COLS_PER_SPLIT / 128)    // 8 col-tiles of 128 per split

// async global->LDS, 16B per lane; lds ptr must be wave-uniform (HW adds lane*16)
#define GLOAD_LDS(gp, lp) __builtin_amdgcn_global_load_lds( \
    (const __attribute__((address_space(1))) void*)(gp),    \
    (__attribute__((address_space(3))) void*)(lp), 16, 0, 0)

__device__ inline ushort_t f2bf(float x) {
    unsigned int u = __float_as_uint(x);
    unsigned int r = (u + 0x7FFFu + ((u >> 16) & 1u)) >> 16;
    return (ushort_t)r;
}
__device__ inline float bf2f(ushort_t h) { return __uint_as_float(((unsigned int)h) << 16); }

// ---------------- Phase A1: per-row inverse norms ----------------
__global__ void norm_kernel(const float* __restrict__ E, float* __restrict__ invn) {
    int row  = blockIdx.x * 4 + (threadIdx.x >> 6);
    int lane = threadIdx.x & 63;
    const float* p = E + (size_t)row * EMB;
    float s = 0.f;
#pragma unroll
    for (int k = 0; k < EMB / 64; ++k) {
        float v = p[lane + k * 64];
        s = fmaf(v, v, s);
    }
#pragma unroll
    for (int off = 32; off > 0; off >>= 1) s += __shfl_down(s, off);
    if (lane == 0) invn[row] = 1.0f / sqrtf(s);
}

// ---------------- Phase A2: fp32 -> bf16 hi/lo split planes ----------------
__global__ void convert_kernel(const float* __restrict__ E,
                               ushort_t* __restrict__ hi, ushort_t* __restrict__ lo) {
    int i = blockIdx.x * 256 + threadIdx.x;     // one float4 per thread
    float4 f = ((const float4*)E)[i];
    float x[4] = {f.x, f.y, f.z, f.w};
    ushort_t h[4], l[4];
#pragma unroll
    for (int q = 0; q < 4; ++q) {
        h[q] = f2bf(x[q]);
        l[q] = f2bf(x[q] - bf2f(h[q]));
    }
    ((ushort4*)hi)[i] = make_ushort4(h[0], h[1], h[2], h[3]);
    ((ushort4*)lo)[i] = make_ushort4(l[0], l[1], l[2], l[3]);
}

// ---------------- Phase B: split-bf16 MFMA GEMM + fused per-row top-6 ----------------
// LDS granule layout for each 128x32-bf16 tile: granule (row, oct) -> slot
//   s = (row&15) + 16*oct + 64*(row>>4)
// => fragment read for (wm, fr) is LDS bytes [(wm*4+fr)*1024 + lane*16), wave-contiguous.
__global__ __launch_bounds__(256, 2) void sim_topk_mfma(
    const ushort_t* __restrict__ Ehi, const ushort_t* __restrict__ Elo,
    const float* __restrict__ invn,
    float* __restrict__ pv, int* __restrict__ pix) {

    __shared__ union {
        struct { ushort_t Ah[4096]; ushort_t Al[4096];
                 ushort_t Bh[4096]; ushort_t Bl[4096]; } s;   // 32 KB staging
        struct { float sims[128 * 132]; } c;                   // 67.6 KB C-tile
        struct { float mv[128][12]; int mi[128][12]; } m;      // 12 KB merge
    } sh;
    __shared__ float invB[128];

    const int t     = threadIdx.x;
    const int lane  = t & 63;
    const int wave  = t >> 6;
    const int wm    = wave >> 1;          // M half (0/1)
    const int wn    = wave & 1;           // N half (0/1)
    const int rb    = blockIdx.x >> 3;
    const int split = blockIdx.x & 7;
    const int row0  = rb * 128;

    // staging decomposition for slot s1 = t (slot s2 = t+256 -> row +64)
    const int so = (t >> 4) & 3;                 // oct
    const int r1 = (t & 15) + 16 * (t >> 6);     // row for slot t

    // per-thread scan identity: row = t>>1, col-half = t&1
    const float invA = invn[row0 + (t >> 1)];

    float tv[6];
    int   ti[6];
#pragma unroll
    for (int s = 0; s < 6; ++s) { tv[s] = -INFINITY; ti[s] = 0x7FFFFFFF; }

    for (int ct = 0; ct < NTILES; ++ct) {
        const int col0 = split * COLS_PER_SPLIT + ct * 128;

        f32x4 acc[4][4];
#pragma unroll
        for (int fr = 0; fr < 4; ++fr)
#pragma unroll
            for (int fc = 0; fc < 4; ++fc)
#pragma unroll
                for (int q = 0; q < 4; ++q) acc[fr][fc][q] = 0.f;

        for (int kk = 0; kk < EMB; kk += 32) {
            __syncthreads();
            {
                const size_t offA = (size_t)(row0 + r1) * EMB + kk + so * 8;
                const size_t offB = (size_t)(col0 + r1) * EMB + kk + so * 8;
                const int lbase = wave * 512;      // ushort units; wave-uniform
                GLOAD_LDS(Ehi + offA,         sh.s.Ah + lbase);
                GLOAD_LDS(Ehi + offA + 32768, sh.s.Ah + 2048 + lbase);   // +64 rows
                GLOAD_LDS(Elo + offA,         sh.s.Al + lbase);
                GLOAD_LDS(Elo + offA + 32768, sh.s.Al + 2048 + lbase);
                GLOAD_LDS(Ehi + offB,         sh.s.Bh + lbase);
                GLOAD_LDS(Ehi + offB + 32768, sh.s.Bh + 2048 + lbase);
                GLOAD_LDS(Elo + offB,         sh.s.Bl + lbase);
                GLOAD_LDS(Elo + offB + 32768, sh.s.Bl + 2048 + lbase);
            }
            __syncthreads();

            bf16x8 ah[4], al[4], bh[4], bl[4];
#pragma unroll
            for (int f = 0; f < 4; ++f) {
                ah[f] = *(const bf16x8*)&sh.s.Ah[(wm * 4 + f) * 512 + lane * 8];
                al[f] = *(const bf16x8*)&sh.s.Al[(wm * 4 + f) * 512 + lane * 8];
                bh[f] = *(const bf16x8*)&sh.s.Bh[(wn * 4 + f) * 512 + lane * 8];
                bl[f] = *(const bf16x8*)&sh.s.Bl[(wn * 4 + f) * 512 + lane * 8];
            }
#pragma unroll
            for (int fr = 0; fr < 4; ++fr)
#pragma unroll
                for (int fc = 0; fc < 4; ++fc) {
                    acc[fr][fc] = __builtin_amdgcn_mfma_f32_16x16x32_bf16(ah[fr], bh[fc], acc[fr][fc], 0, 0, 0);
                    acc[fr][fc] = __builtin_amdgcn_mfma_f32_16x16x32_bf16(ah[fr], bl[fc], acc[fr][fc], 0, 0, 0);
                    acc[fr][fc] = __builtin_amdgcn_mfma_f32_16x16x32_bf16(al[fr], bh[fc], acc[fr][fc], 0, 0, 0);
                }
        }

        // ---- C-tile to LDS, scaled scan, top-6 update ----
        __syncthreads();
        if (t < 128) invB[t] = invn[col0 + t];
        {
            const int cq = lane >> 4, cc = lane & 15;
#pragma unroll
            for (int fr = 0; fr < 4; ++fr) {
                const int rbase = wm * 64 + fr * 16 + cq * 4;
#pragma unroll
                for (int fc = 0; fc < 4; ++fc) {
                    const int c = wn * 64 + fc * 16 + cc;
#pragma unroll
                    for (int q = 0; q < 4; ++q)
                        sh.c.sims[(rbase + q) * 132 + c] = acc[fr][fc][q];
                }
            }
        }
        __syncthreads();
        {
            const int srow = t >> 1, c0 = (t & 1) << 6;
            const float* rowp = &sh.c.sims[srow * 132 + c0];
#pragma unroll 4
            for (int j = 0; j < 64; j += 4) {
                float4 v4 = *(const float4*)(rowp + j);
                float vals[4] = {v4.x, v4.y, v4.z, v4.w};
#pragma unroll
                for (int q = 0; q < 4; ++q) {
                    float sv = vals[q] * invA * invB[c0 + j + q];
                    if (sv > tv[5]) {          // strict >: earlier (lower idx) survives ties
                        float cv = sv; int ci = col0 + c0 + j + q;
#pragma unroll
                        for (int s = 0; s < 6; ++s) {
                            if (cv > tv[s]) {
                                float tf = tv[s]; int tii = ti[s];
                                tv[s] = cv; ti[s] = ci; cv = tf; ci = tii;
                            }
                        }
                    }
                }
            }
        }
    }

    // ---- merge thread pairs, emit per-(row,split) top-6 ----
    __syncthreads();
    {
        const int srow = t >> 1, half = t & 1;
#pragma unroll
        for (int s = 0; s < 6; ++s) {
            sh.m.mv[srow][half * 6 + s] = tv[s];
            sh.m.mi[srow][half * 6 + s] = ti[s];
        }
    }
    __syncthreads();
    if (t < 128) {
        int p = 0, q = 0;
        const size_t base = ((size_t)(row0 + t) * NSPLIT + split) * 6;
#pragma unroll
        for (int sel = 0; sel < 6; ++sel) {
            float v1 = sh.m.mv[t][p],     v2 = sh.m.mv[t][6 + q];
            int   i1 = sh.m.mi[t][p],     i2 = sh.m.mi[t][6 + q];
            bool take1 = (v1 > v2) || (v1 == v2 && i1 < i2);
            pv[base + sel]  = take1 ? v1 : v2;
            pix[base + sel] = take1 ? i1 : i2;
            if (take1) ++p; else ++q;
        }
    }
}

// ---------------- Phase C: 8-way merge of sorted partials + gather + output ----------------
__global__ void finalize_kernel(
    const float* __restrict__ pv, const int* __restrict__ pix,
    const int* __restrict__ n_users, const int* __restrict__ n_entitys,
    const int* __restrict__ interactions, float* __restrict__ out) {

    int row = blockIdx.x * blockDim.x + threadIdx.x;
    if (row >= NROWS) return;

    int ent = n_entitys[row];
    int p[NSPLIT];
#pragma unroll
    for (int s = 0; s < NSPLIT; ++s) p[s] = 0;

    float sum = 0.f;
    for (int sel = 0; sel < 6; ++sel) {
        float bv = -INFINITY; int bi = 0x7FFFFFFF; int bs = 0;
#pragma unroll
        for (int s = 0; s < NSPLIT; ++s) {
            size_t base = ((size_t)row * NSPLIT + s) * 6 + p[s];
            float v = pv[base]; int id = pix[base];
            if (v > bv || (v == bv && id < bi)) { bv = v; bi = id; bs = s; }
        }
#pragma unroll
        for (int s = 0; s < NSPLIT; ++s) if (s == bs) p[s]++;
        int uid = n_users[bi];
        float memb = (float)interactions[(size_t)uid * NITEMS + ent];
        sum = fmaf(bv, memb, sum);
    }
    out[row] = sum * (1.0f / 6.0f);
}

extern "C" void kernel_launch(void* const* d_in, const int* in_sizes, int n_in,
                              void* d_out, int out_size, void* d_ws, size_t ws_size,
                              hipStream_t stream) {
    const float* E            = (const float*)d_in[0];
    const int*   n_users      = (const int*)d_in[1];
    const int*   n_entitys    = (const int*)d_in[2];
    const int*   interactions = (const int*)d_in[3];
    float*       out          = (float*)d_out;

    // workspace: Ehi[4.19M u16] | Elo[4.19M u16] | invn[8192 f] | pv[393216 f] | pix[393216 i]
    // total ~19.9 MB
    ushort_t* Ehi  = (ushort_t*)d_ws;
    ushort_t* Elo  = Ehi + (size_t)NROWS * EMB;
    float*    invn = (float*)(Elo + (size_t)NROWS * EMB);
    float*    pv   = invn + NROWS;
    int*      pix  = (int*)(pv + (size_t)NROWS * NSPLIT * 6);

    norm_kernel<<<NROWS / 4, 256, 0, stream>>>(E, invn);
    convert_kernel<<<(NROWS * EMB / 4) / 256, 256, 0, stream>>>(E, Ehi, Elo);
    sim_topk_mfma<<<(NROWS / 128) * NSPLIT, 256, 0, stream>>>(Ehi, Elo, invn, pv, pix);
    finalize_kernel<<<(NROWS + 255) / 256, 256, 0, stream>>>(pv, pix, n_users, n_entitys,
                                                             interactions, out);
}

// Round 4
// 457.743 us; speedup vs baseline: 2.8992x; 1.3644x over previous
//
#include <hip/hip_runtime.h>
#include <math.h>

typedef unsigned short ushort_t;
typedef unsigned int   uint32;
typedef __attribute__((ext_vector_type(8)))  short bf16x8;
typedef __attribute__((ext_vector_type(16))) float f32x16;

#define EMB     512
#define NROWS   8192
#define NITEMS  4096
#define NSPLIT  8
#define CPS     1024     // candidates per split
#define NTILES  8        // 128-candidate tiles per split
#define LDEPTH  12       // per-lane key-list depth
#define KEEP    16       // keys emitted per (query,split)

// async global->LDS, 16B/lane; LDS dst = wave-uniform base + lane*16
#define GLOAD_LDS(gp, lp) __builtin_amdgcn_global_load_lds( \
    (const __attribute__((address_space(1))) void*)(gp),    \
    (__attribute__((address_space(3))) void*)(lp), 16, 0, 0)

__device__ inline ushort_t f2bf(float x) {
    uint32 u = __float_as_uint(x);
    uint32 r = (u + 0x7FFFu + ((u >> 16) & 1u)) >> 16;
    return (ushort_t)r;
}

// monotone float->u32, truncate low 13 bits, embed (8191-idx) for lowest-idx-wins ties
__device__ inline uint32 packkey(float v, int idx) {
    uint32 u = __float_as_uint(v);
    uint32 s = u ^ ((u & 0x80000000u) ? 0xFFFFFFFFu : 0x80000000u);
    return (s & 0xFFFFE000u) | ((uint32)idx ^ 0x1FFFu);
}

// ---------------- Phase A: fp64 norms + normalized-bf16 plane ----------------
__global__ void prep_kernel(const float* __restrict__ E,
                            ushort_t* __restrict__ Xbf, double* __restrict__ invd) {
    const int row  = blockIdx.x * 4 + (threadIdx.x >> 6);
    const int lane = threadIdx.x & 63;
    const float4* p = (const float4*)(E + (size_t)row * EMB);
    float4 f0 = p[lane];
    float4 f1 = p[lane + 64];
    double s = (double)f0.x*f0.x + (double)f0.y*f0.y + (double)f0.z*f0.z + (double)f0.w*f0.w
             + (double)f1.x*f1.x + (double)f1.y*f1.y + (double)f1.z*f1.z + (double)f1.w*f1.w;
#pragma unroll
    for (int m = 32; m > 0; m >>= 1) s += __shfl_xor(s, m);
    const double inv = 1.0 / sqrt(s);
    if (lane == 0) invd[row] = inv;
    const float invf = (float)inv;
    float x[8] = {f0.x, f0.y, f0.z, f0.w, f1.x, f1.y, f1.z, f1.w};
    ushort_t h[8];
#pragma unroll
    for (int q = 0; q < 8; ++q) h[q] = f2bf(x[q] * invf);
    ushort4* H = (ushort4*)(Xbf + (size_t)row * EMB);
    H[lane]      = make_ushort4(h[0], h[1], h[2], h[3]);
    H[lane + 64] = make_ushort4(h[4], h[5], h[6], h[7]);
}

// ---------------- Phase B: bf16 32x32x16 MFMA + packed-key top-12/lane ----------------
// LDS granule layout per 128x64 tile: slot(row,oct) =
//   (row>>5)*256 + (oct>>1)*64 + (oct&1)*32 + (row&31)
// frag (rb5,kt): slot = rb5*256 + kt*64 + lane  (wave-contiguous 1KB b128 reads)
__global__ __launch_bounds__(256, 2) void sim_topk_mfma(
    const ushort_t* __restrict__ Xbf, uint32* __restrict__ keys_out) {

    __shared__ union {
        struct { ushort_t Ah[8192]; ushort_t Bh[8192]; } s;  // 32 KB staging
        struct { uint32 mk[128][65]; } m;                     // 33.3 KB merge (padded pitch)
    } sh;

    const int t     = threadIdx.x;
    const int lane  = t & 63;
    const int wave  = t >> 6;
    const int wm    = wave >> 1;
    const int wn    = wave & 1;
    const int rb    = blockIdx.x >> 3;
    const int split = blockIdx.x & 7;
    const int qbase = rb * 128;
    const int srow  = wave * 32 + (lane & 31);
    const int shalf = lane >> 5;

    uint32 tv[2][LDEPTH];
#pragma unroll
    for (int fc = 0; fc < 2; ++fc)
#pragma unroll
        for (int s = 0; s < LDEPTH; ++s) tv[fc][s] = 0u;

#pragma unroll 1
    for (int ct = 0; ct < NTILES; ++ct) {
        const int cand0 = split * CPS + ct * 128;

        f32x16 acc[2][2];
#pragma unroll
        for (int fr = 0; fr < 2; ++fr)
#pragma unroll
            for (int fc = 0; fc < 2; ++fc)
#pragma unroll
                for (int q = 0; q < 16; ++q) acc[fr][fc][q] = 0.f;

#pragma unroll 1
        for (int kk = 0; kk < EMB; kk += 64) {
            __syncthreads();
#pragma unroll
            for (int c = 0; c < 4; ++c) {
                const int koff = kk + (c * 2 + shalf) * 8;
                const int lb   = (wave * 4 + c) * 512;          // wave-uniform ushort offset
                GLOAD_LDS(Xbf + (size_t)(cand0 + srow) * EMB + koff, sh.s.Ah + lb);
                GLOAD_LDS(Xbf + (size_t)(qbase + srow) * EMB + koff, sh.s.Bh + lb);
            }
            __syncthreads();

            bf16x8 aH[2][4], bH[2][4];
#pragma unroll
            for (int f = 0; f < 2; ++f)
#pragma unroll
                for (int kt = 0; kt < 4; ++kt) {
                    aH[f][kt] = *(const bf16x8*)&sh.s.Ah[((wm * 2 + f) * 256 + kt * 64 + lane) * 8];
                    bH[f][kt] = *(const bf16x8*)&sh.s.Bh[((wn * 2 + f) * 256 + kt * 64 + lane) * 8];
                }
#pragma unroll
            for (int fr = 0; fr < 2; ++fr)
#pragma unroll
                for (int fc = 0; fc < 2; ++fc)
#pragma unroll
                    for (int kt = 0; kt < 4; ++kt)
                        acc[fr][fc] = __builtin_amdgcn_mfma_f32_32x32x16_bf16(
                            aH[fr][kt], bH[fc][kt], acc[fr][fc], 0, 0, 0);
        }

        // ---- epilogue: packed-key insert into per-lane top-12 ----
#pragma unroll
        for (int fc = 0; fc < 2; ++fc) {
#pragma unroll
            for (int fr = 0; fr < 2; ++fr) {
                float m0 = fmaxf(fmaxf(acc[fr][fc][0],  acc[fr][fc][1]),  fmaxf(acc[fr][fc][2],  acc[fr][fc][3]));
                float m1 = fmaxf(fmaxf(acc[fr][fc][4],  acc[fr][fc][5]),  fmaxf(acc[fr][fc][6],  acc[fr][fc][7]));
                float m2 = fmaxf(fmaxf(acc[fr][fc][8],  acc[fr][fc][9]),  fmaxf(acc[fr][fc][10], acc[fr][fc][11]));
                float m3 = fmaxf(fmaxf(acc[fr][fc][12], acc[fr][fc][13]), fmaxf(acc[fr][fc][14], acc[fr][fc][15]));
                float mx = fmaxf(fmaxf(m0, m1), fmaxf(m2, m3));
                if (packkey(mx, 0) > tv[fc][LDEPTH - 1]) {
                    const int jb = cand0 + wm * 64 + fr * 32 + (shalf << 2);
#pragma unroll
                    for (int reg = 0; reg < 16; ++reg) {
                        const int ci = jb + (reg & 3) + ((reg >> 2) << 3);
                        uint32 key = packkey(acc[fr][fc][reg], ci);
                        if (key > tv[fc][LDEPTH - 1]) {
                            uint32 cur = key;
#pragma unroll
                            for (int s = 0; s < LDEPTH; ++s) {
                                uint32 a  = tv[fc][s];
                                bool   gt = cur > a;
                                tv[fc][s] = gt ? cur : a;
                                cur       = gt ? a : cur;
                            }
                        }
                    }
                }
            }
        }
    }

    // ---- merge 4 lane-lists per query, emit sorted top-16 keys ----
    __syncthreads();
#pragma unroll
    for (int fc = 0; fc < 2; ++fc) {
        const int col = wn * 64 + fc * 32 + (lane & 31);
        const int sl  = wm * 2 + shalf;
#pragma unroll
        for (int s = 0; s < LDEPTH; ++s) sh.m.mk[col][sl * 16 + s] = tv[fc][s];
#pragma unroll
        for (int s = LDEPTH; s < 16; ++s) sh.m.mk[col][sl * 16 + s] = 0u;
    }
    __syncthreads();
    if (t < 128) {
        int p[4] = {0, 0, 0, 0};
        const size_t base = ((size_t)(qbase + t) * NSPLIT + split) * KEEP;
#pragma unroll 1
        for (int sel = 0; sel < KEEP; ++sel) {
            uint32 bk = 0; int bl = 0;
#pragma unroll
            for (int l = 0; l < 4; ++l) {
                uint32 k = sh.m.mk[t][l * 16 + p[l]];
                if (k > bk) { bk = k; bl = l; }
            }
            p[bl]++;
            keys_out[base + sel] = bk;
        }
    }
}

// ---------------- Phase C: merge 8 splits, fp64 exact rescue, output ----------------
__global__ __launch_bounds__(256) void rescue_kernel(
    const float* __restrict__ E, const double* __restrict__ invd,
    const uint32* __restrict__ keys,
    const int* __restrict__ n_users, const int* __restrict__ n_entitys,
    const int* __restrict__ interactions, float* __restrict__ out) {

    __shared__ uint32 fk[4][NSPLIT * KEEP];   // 4 rows x 128 keys
    __shared__ double dsim[4][16];
    __shared__ int    dcand[4][16];

    const int t    = threadIdx.x;
    const int lane = t & 63;
    const int w    = t >> 6;
    const int row0 = blockIdx.x * 4;

    {   // stage this block's 512 keys
        uint32* flat = &fk[0][0];
        flat[t]       = keys[(size_t)row0 * 128 + t];
        flat[t + 256] = keys[(size_t)row0 * 128 + t + 256];
    }
    __syncthreads();

    const int row = row0 + w;
    const int g   = lane >> 2;     // candidate slot 0..15
    const int r   = lane & 3;      // k-quarter

    // wave-redundant 8-way merge -> global approx top-16 (one candidate per group)
    int p[NSPLIT];
#pragma unroll
    for (int s = 0; s < NSPLIT; ++s) p[s] = 0;
    int mycand = 0;
#pragma unroll 1
    for (int sel = 0; sel < 16; ++sel) {
        uint32 bk = 0; int bs = 0;
#pragma unroll
        for (int s = 0; s < NSPLIT; ++s) {
            uint32 k = fk[w][s * 16 + p[s]];
            if (k > bk) { bk = k; bs = s; }
        }
        p[bs]++;
        if (g == sel) mycand = (int)((bk & 0x1FFFu) ^ 0x1FFFu);
    }

    // exact fp64 dot: group g scores candidate mycand; lane r covers k in [r*128, r*128+128)
    const float4* Q = (const float4*)(E + (size_t)row    * EMB);
    const float4* C = (const float4*)(E + (size_t)mycand * EMB);
    double acc = 0.0;
#pragma unroll 8
    for (int j = 0; j < 32; ++j) {
        float4 q = Q[r * 32 + j];
        float4 c = C[r * 32 + j];
        acc += (double)q.x * c.x + (double)q.y * c.y
             + (double)q.z * c.z + (double)q.w * c.w;
    }
    acc += __shfl_xor(acc, 1);
    acc += __shfl_xor(acc, 2);
    const double sim = acc * invd[row] * invd[mycand];
    if (r == 0) { dsim[w][g] = sim; dcand[w][g] = mycand; }
    __syncthreads();

    if (lane == 0) {
        const int ent = n_entitys[row];
        unsigned used = 0;
        double sum = 0.0;
#pragma unroll 1
        for (int sel = 0; sel < 6; ++sel) {
            double bv = -1e300; int bi = 0x7FFFFFFF; int bg = 0;
#pragma unroll
            for (int i = 0; i < 16; ++i) {
                if (!((used >> i) & 1u)) {
                    double v = dsim[w][i]; int id = dcand[w][i];
                    if (v > bv || (v == bv && id < bi)) { bv = v; bi = id; bg = i; }
                }
            }
            used |= 1u << bg;
            const int uid = n_users[bi];
            sum += bv * (double)interactions[(size_t)uid * NITEMS + ent];
        }
        out[row] = (float)(sum * (1.0 / 6.0));
    }
}

extern "C" void kernel_launch(void* const* d_in, const int* in_sizes, int n_in,
                              void* d_out, int out_size, void* d_ws, size_t ws_size,
                              hipStream_t stream) {
    const float* E            = (const float*)d_in[0];
    const int*   n_users      = (const int*)d_in[1];
    const int*   n_entitys    = (const int*)d_in[2];
    const int*   interactions = (const int*)d_in[3];
    float*       out          = (float*)d_out;

    // ws: Xbf[8 MB] | invd[64 KB] | keys[4 MB]  (~12.2 MB)
    ushort_t* Xbf  = (ushort_t*)d_ws;
    double*   invd = (double*)(Xbf + (size_t)NROWS * EMB);
    uint32*   keys = (uint32*)(invd + NROWS);

    prep_kernel<<<NROWS / 4, 256, 0, stream>>>(E, Xbf, invd);
    sim_topk_mfma<<<(NROWS / 128) * NSPLIT, 256, 0, stream>>>(Xbf, keys);
    rescue_kernel<<<NROWS / 4, 256, 0, stream>>>(E, invd, keys, n_users, n_entitys,
                                                 interactions, out);
}

// Round 5
// 430.982 us; speedup vs baseline: 3.0792x; 1.0621x over previous
//
#include <hip/hip_runtime.h>
#include <math.h>

typedef unsigned short ushort_t;
typedef unsigned int   uint32;
typedef __attribute__((ext_vector_type(8)))  short bf16x8;
typedef __attribute__((ext_vector_type(16))) float f32x16;

#define EMB     512
#define NROWS   8192
#define NITEMS  4096
#define NSPLIT  8
#define CPS     1024     // candidates per split
#define CTILE   256      // candidate tile (4 per split)
#define QTILE   128      // queries per block
#define KSLAB   32       // K per staged step
#define NSTEPS  64       // 4 ct * 16 kk
#define LDEPTH  12
#define KEEP    16

#define GLOAD_LDS(gp, lp) __builtin_amdgcn_global_load_lds( \
    (const __attribute__((address_space(1))) void*)(gp),    \
    (__attribute__((address_space(3))) void*)(lp), 16, 0, 0)

__device__ inline ushort_t f2bf(float x) {
    uint32 u = __float_as_uint(x);
    uint32 r = (u + 0x7FFFu + ((u >> 16) & 1u)) >> 16;
    return (ushort_t)r;
}

// monotone float->u32, truncate low 13 bits, embed (8191-idx): lowest idx wins ties
__device__ inline uint32 packkey(float v, int idx) {
    uint32 u = __float_as_uint(v);
    uint32 s = u ^ ((u & 0x80000000u) ? 0xFFFFFFFFu : 0x80000000u);
    return (s & 0xFFFFE000u) | ((uint32)idx ^ 0x1FFFu);
}

// ---------------- Phase A: fp64 norms + normalized-bf16 plane ----------------
__global__ void prep_kernel(const float* __restrict__ E,
                            ushort_t* __restrict__ Xbf, double* __restrict__ invd) {
    const int row  = blockIdx.x * 4 + (threadIdx.x >> 6);
    const int lane = threadIdx.x & 63;
    const float4* p = (const float4*)(E + (size_t)row * EMB);
    float4 f0 = p[lane];
    float4 f1 = p[lane + 64];
    double s = (double)f0.x*f0.x + (double)f0.y*f0.y + (double)f0.z*f0.z + (double)f0.w*f0.w
             + (double)f1.x*f1.x + (double)f1.y*f1.y + (double)f1.z*f1.z + (double)f1.w*f1.w;
#pragma unroll
    for (int m = 32; m > 0; m >>= 1) s += __shfl_xor(s, m);
    const double inv = 1.0 / sqrt(s);
    if (lane == 0) invd[row] = inv;
    const float invf = (float)inv;
    float x[8] = {f0.x, f0.y, f0.z, f0.w, f1.x, f1.y, f1.z, f1.w};
    ushort_t h[8];
#pragma unroll
    for (int q = 0; q < 8; ++q) h[q] = f2bf(x[q] * invf);
    ushort4* H = (ushort4*)(Xbf + (size_t)row * EMB);
    H[lane]      = make_ushort4(h[0], h[1], h[2], h[3]);
    H[lane + 64] = make_ushort4(h[4], h[5], h[6], h[7]);
}

// ---------------- Phase B: dbuf bf16 32x32x16 MFMA, 256x128 tile, top-12/lane ----------------
// Staging granule (row, oct) of a (rows x 32K) tile -> slot G*64 + l, where
// G = (row>>5)*2 + (oct>>1), l = (oct&1)*32 + (row&31).
// Frag (FR, kt) read = region + (FR*128 + kt*64 + lane)*16B : wave-contiguous 1KB.
__global__ __launch_bounds__(256, 2) void sim_topk_mfma(
    const ushort_t* __restrict__ Xbf, uint32* __restrict__ keys_out) {

    __shared__ union {
        struct { ushort_t A[2][8192]; ushort_t B[2][4096]; } s;  // 48 KB dbuf staging
        struct { uint32 mk[128][65]; } m;                         // 33.3 KB merge
    } sh;

    const int t     = threadIdx.x;
    const int lane  = t & 63;
    const int wave  = t >> 6;
    const int wm    = wave >> 1;          // candidate half (0/1): rows wm*128..+128
    const int wn    = wave & 1;           // query half (0/1): cols wn*64..+64
    const int rb    = blockIdx.x >> 3;
    const int split = blockIdx.x & 7;
    const int qbase = rb * QTILE;
    const int l31   = lane & 31;
    const int l5    = lane >> 5;

    // per-(wave,c) staging descriptors: G = wave*6+c; G<16 -> A(256 rows), else B(128 rows)
    int  laneoff[6];   // ushort units: row*EMB + oct*8 (row within tile)
    int  ldsoff[6];    // ushort units within A- or B-region
    bool isA[6];
#pragma unroll
    for (int c = 0; c < 6; ++c) {
        const int G = wave * 6 + c;
        const bool a = (G < 16);
        const int idx = a ? G : (G - 16);
        const int row = (idx >> 1) * 32 + l31;
        const int oct = (idx & 1) * 2 + l5;
        laneoff[c] = row * EMB + oct * 8;
        ldsoff[c]  = idx * 512;
        isA[c]     = a;
    }
    const int qoff = qbase * EMB;

    auto stage = [&](int cand0, int kk, int buf) {
#pragma unroll
        for (int c = 0; c < 6; ++c) {
            const int goff = laneoff[c] + kk + (isA[c] ? cand0 * EMB : qoff);
            ushort_t* lp = isA[c] ? (sh.s.A[buf] + ldsoff[c]) : (sh.s.B[buf] + ldsoff[c]);
            GLOAD_LDS(Xbf + goff, lp);
        }
    };

    uint32 tv[2][LDEPTH];
#pragma unroll
    for (int fc = 0; fc < 2; ++fc)
#pragma unroll
        for (int s = 0; s < LDEPTH; ++s) tv[fc][s] = 0u;

    f32x16 acc[4][2];
#pragma unroll
    for (int fr = 0; fr < 4; ++fr)
#pragma unroll
        for (int fc = 0; fc < 2; ++fc)
#pragma unroll
            for (int q = 0; q < 16; ++q) acc[fr][fc][q] = 0.f;

    stage(split * CPS + 0 * CTILE, 0, 0);   // prologue: step 0 -> buf 0

#pragma unroll 1
    for (int s = 0; s < NSTEPS; ++s) {
        const int ct   = s >> 4;
        const int buf  = s & 1;
        const int cand0 = split * CPS + ct * CTILE;

        __syncthreads();   // drains this step's DMA (issued one compute-phase ago)

        if (s + 1 < NSTEPS) {
            const int s2 = s + 1;
            stage(split * CPS + (s2 >> 4) * CTILE, (s2 & 15) * KSLAB, s2 & 1);
        }

        bf16x8 aH[4][2], bH[2][2];
#pragma unroll
        for (int fr = 0; fr < 4; ++fr)
#pragma unroll
            for (int kt = 0; kt < 2; ++kt)
                aH[fr][kt] = *(const bf16x8*)&sh.s.A[buf][((wm * 4 + fr) * 128 + kt * 64 + lane) * 8];
#pragma unroll
        for (int fc = 0; fc < 2; ++fc)
#pragma unroll
            for (int kt = 0; kt < 2; ++kt)
                bH[fc][kt] = *(const bf16x8*)&sh.s.B[buf][((wn * 2 + fc) * 128 + kt * 64 + lane) * 8];

#pragma unroll
        for (int kt = 0; kt < 2; ++kt)
#pragma unroll
            for (int fr = 0; fr < 4; ++fr)
#pragma unroll
                for (int fc = 0; fc < 2; ++fc)
                    acc[fr][fc] = __builtin_amdgcn_mfma_f32_32x32x16_bf16(
                        aH[fr][kt], bH[fc][kt], acc[fr][fc], 0, 0, 0);

        if ((s & 15) == 15) {
            // ---- register-only epilogue: packed-key insert into per-lane top-12 ----
#pragma unroll
            for (int fc = 0; fc < 2; ++fc) {
#pragma unroll
                for (int fr = 0; fr < 4; ++fr) {
                    float m0 = fmaxf(fmaxf(acc[fr][fc][0],  acc[fr][fc][1]),  fmaxf(acc[fr][fc][2],  acc[fr][fc][3]));
                    float m1 = fmaxf(fmaxf(acc[fr][fc][4],  acc[fr][fc][5]),  fmaxf(acc[fr][fc][6],  acc[fr][fc][7]));
                    float m2 = fmaxf(fmaxf(acc[fr][fc][8],  acc[fr][fc][9]),  fmaxf(acc[fr][fc][10], acc[fr][fc][11]));
                    float m3 = fmaxf(fmaxf(acc[fr][fc][12], acc[fr][fc][13]), fmaxf(acc[fr][fc][14], acc[fr][fc][15]));
                    float mx = fmaxf(fmaxf(m0, m1), fmaxf(m2, m3));
                    if (packkey(mx, 0) > tv[fc][LDEPTH - 1]) {
                        const int jb = cand0 + wm * 128 + fr * 32 + (l5 << 2);
#pragma unroll
                        for (int reg = 0; reg < 16; ++reg) {
                            const int ci = jb + (reg & 3) + ((reg >> 2) << 3);
                            uint32 key = packkey(acc[fr][fc][reg], ci);
                            if (key > tv[fc][LDEPTH - 1]) {
                                uint32 cur = key;
#pragma unroll
                                for (int d = 0; d < LDEPTH; ++d) {
                                    uint32 a  = tv[fc][d];
                                    bool   gt = cur > a;
                                    tv[fc][d] = gt ? cur : a;
                                    cur       = gt ? a : cur;
                                }
                            }
                        }
                    }
#pragma unroll
                    for (int q = 0; q < 16; ++q) acc[fr][fc][q] = 0.f;
                }
            }
        }
    }

    // ---- merge 4 lane-lists per query, emit sorted top-16 keys ----
    __syncthreads();
#pragma unroll
    for (int fc = 0; fc < 2; ++fc) {
        const int col = wn * 64 + fc * 32 + l31;
        const int sl  = wm * 2 + l5;
#pragma unroll
        for (int d = 0; d < LDEPTH; ++d) sh.m.mk[col][sl * 16 + d] = tv[fc][d];
#pragma unroll
        for (int d = LDEPTH; d < 16; ++d) sh.m.mk[col][sl * 16 + d] = 0u;
    }
    __syncthreads();
    if (t < 128) {
        int p[4] = {0, 0, 0, 0};
        const size_t base = ((size_t)(qbase + t) * NSPLIT + split) * KEEP;
#pragma unroll 1
        for (int sel = 0; sel < KEEP; ++sel) {
            uint32 bk = 0; int bl = 0;
#pragma unroll
            for (int l = 0; l < 4; ++l) {
                uint32 k = sh.m.mk[t][l * 16 + p[l]];
                if (k > bk) { bk = k; bl = l; }
            }
            p[bl]++;
            keys_out[base + sel] = bk;
        }
    }
}

// ---------------- Phase C: rank-select merge + fp64 exact rescue + output ----------------
__global__ __launch_bounds__(256) void rescue_kernel(
    const float* __restrict__ E, const double* __restrict__ invd,
    const uint32* __restrict__ keys,
    const int* __restrict__ n_users, const int* __restrict__ n_entitys,
    const int* __restrict__ interactions, float* __restrict__ out) {

    __shared__ uint32 fk[4][NSPLIT * KEEP];   // 4 rows x 128 keys
    __shared__ int    scand[4][16];
    __shared__ double dsim[4][16];
    __shared__ int    dcand[4][16];

    const int t    = threadIdx.x;
    const int lane = t & 63;
    const int w    = t >> 6;
    const int row0 = blockIdx.x * 4;

    {
        uint32* flat = &fk[0][0];
        flat[t]       = keys[(size_t)row0 * 128 + t];
        flat[t + 256] = keys[(size_t)row0 * 128 + t + 256];
    }
    __syncthreads();

    const int row = row0 + w;

    // parallel rank-select: lane owns key slots (lane, lane+64); keys are unique
    {
        const uint32 k0 = fk[w][lane], k1 = fk[w][lane + 64];
        int r0 = 0, r1 = 0;
#pragma unroll 8
        for (int j = 0; j < 128; ++j) {
            const uint32 kb = fk[w][j];     // broadcast read
            r0 += (kb > k0);
            r1 += (kb > k1);
        }
        if (r0 < 16) scand[w][r0] = (int)((k0 & 0x1FFFu) ^ 0x1FFFu);
        if (r1 < 16) scand[w][r1] = (int)((k1 & 0x1FFFu) ^ 0x1FFFu);
    }
    __syncthreads();

    const int g = lane >> 2;       // candidate slot 0..15
    const int r = lane & 3;        // K quarter
    const int mycand = scand[w][g];

    const float4* Q = (const float4*)(E + (size_t)row    * EMB);
    const float4* C = (const float4*)(E + (size_t)mycand * EMB);
    double acc = 0.0;
#pragma unroll 8
    for (int j = 0; j < 32; ++j) {
        float4 q = Q[r * 32 + j];
        float4 c = C[r * 32 + j];
        acc += (double)q.x * c.x + (double)q.y * c.y
             + (double)q.z * c.z + (double)q.w * c.w;
    }
    acc += __shfl_xor(acc, 1);
    acc += __shfl_xor(acc, 2);
    const double sim = acc * invd[row] * invd[mycand];
    if (r == 0) { dsim[w][g] = sim; dcand[w][g] = mycand; }
    __syncthreads();

    if (lane == 0) {
        const int ent = n_entitys[row];
        unsigned used = 0;
        double sum = 0.0;
#pragma unroll 1
        for (int sel = 0; sel < 6; ++sel) {
            double bv = -1e300; int bi = 0x7FFFFFFF; int bg = 0;
#pragma unroll
            for (int i = 0; i < 16; ++i) {
                if (!((used >> i) & 1u)) {
                    double v = dsim[w][i]; int id = dcand[w][i];
                    if (v > bv || (v == bv && id < bi)) { bv = v; bi = id; bg = i; }
                }
            }
            used |= 1u << bg;
            const int uid = n_users[bi];
            sum += bv * (double)interactions[(size_t)uid * NITEMS + ent];
        }
        out[row] = (float)(sum * (1.0 / 6.0));
    }
}

extern "C" void kernel_launch(void* const* d_in, const int* in_sizes, int n_in,
                              void* d_out, int out_size, void* d_ws, size_t ws_size,
                              hipStream_t stream) {
    const float* E            = (const float*)d_in[0];
    const int*   n_users      = (const int*)d_in[1];
    const int*   n_entitys    = (const int*)d_in[2];
    const int*   interactions = (const int*)d_in[3];
    float*       out          = (float*)d_out;

    ushort_t* Xbf  = (ushort_t*)d_ws;
    double*   invd = (double*)(Xbf + (size_t)NROWS * EMB);
    uint32*   keys = (uint32*)(invd + NROWS);

    prep_kernel<<<NROWS / 4, 256, 0, stream>>>(E, Xbf, invd);
    sim_topk_mfma<<<(NROWS / QTILE) * NSPLIT, 256, 0, stream>>>(Xbf, keys);
    rescue_kernel<<<NROWS / 4, 256, 0, stream>>>(E, invd, keys, n_users, n_entitys,
                                                 interactions, out);
}

// Round 6
// 410.618 us; speedup vs baseline: 3.2319x; 1.0496x over previous
//
#include <hip/hip_runtime.h>
#include <math.h>

typedef unsigned short ushort_t;
typedef unsigned int   uint32;
typedef __attribute__((ext_vector_type(8)))  short bf16x8;
typedef __attribute__((ext_vector_type(16))) float f32x16;

#define EMB     512
#define NROWS   8192
#define NITEMS  4096
#define NSPLIT  8
#define CPS     1024     // candidates per split
#define CTILE   256      // candidate tile (4 per split)
#define QTILE   128      // queries per block
#define KSLAB   32       // K per staged step
#define NSTEPS  64       // 4 ct * 16 kk
#define LDEPTH  12
#define KEEP    16

#define GLOAD_LDS(gp, lp) __builtin_amdgcn_global_load_lds( \
    (const __attribute__((address_space(1))) void*)(gp),    \
    (__attribute__((address_space(3))) void*)(lp), 16, 0, 0)

__device__ inline ushort_t f2bf(float x) {
    uint32 u = __float_as_uint(x);
    uint32 r = (u + 0x7FFFu + ((u >> 16) & 1u)) >> 16;
    return (ushort_t)r;
}

// monotone float->u32, truncate low 13 bits, embed (8191-idx): lowest idx wins ties
__device__ inline uint32 packkey(float v, int idx) {
    uint32 u = __float_as_uint(v);
    uint32 s = u ^ ((u & 0x80000000u) ? 0xFFFFFFFFu : 0x80000000u);
    return (s & 0xFFFFE000u) | ((uint32)idx ^ 0x1FFFu);
}

// ---------------- Phase A: fp64 norms + normalized-bf16 plane ----------------
__global__ void prep_kernel(const float* __restrict__ E,
                            ushort_t* __restrict__ Xbf, double* __restrict__ invd) {
    const int row  = blockIdx.x * 4 + (threadIdx.x >> 6);
    const int lane = threadIdx.x & 63;
    const float4* p = (const float4*)(E + (size_t)row * EMB);
    float4 f0 = p[lane];
    float4 f1 = p[lane + 64];
    double s = (double)f0.x*f0.x + (double)f0.y*f0.y + (double)f0.z*f0.z + (double)f0.w*f0.w
             + (double)f1.x*f1.x + (double)f1.y*f1.y + (double)f1.z*f1.z + (double)f1.w*f1.w;
#pragma unroll
    for (int m = 32; m > 0; m >>= 1) s += __shfl_xor(s, m);
    const double inv = 1.0 / sqrt(s);
    if (lane == 0) invd[row] = inv;
    const float invf = (float)inv;
    float x[8] = {f0.x, f0.y, f0.z, f0.w, f1.x, f1.y, f1.z, f1.w};
    ushort_t h[8];
#pragma unroll
    for (int q = 0; q < 8; ++q) h[q] = f2bf(x[q] * invf);
    ushort4* H = (ushort4*)(Xbf + (size_t)row * EMB);
    H[lane]      = make_ushort4(h[0], h[1], h[2], h[3]);
    H[lane + 64] = make_ushort4(h[4], h[5], h[6], h[7]);
}

// ---------------- Phase B: dbuf bf16 32x32x16 MFMA, 256x128 tile, top-12/lane ----------------
// (unchanged from round 5)
__global__ __launch_bounds__(256, 2) void sim_topk_mfma(
    const ushort_t* __restrict__ Xbf, uint32* __restrict__ keys_out) {

    __shared__ union {
        struct { ushort_t A[2][8192]; ushort_t B[2][4096]; } s;  // 48 KB dbuf staging
        struct { uint32 mk[128][65]; } m;                         // 33.3 KB merge
    } sh;

    const int t     = threadIdx.x;
    const int lane  = t & 63;
    const int wave  = t >> 6;
    const int wm    = wave >> 1;
    const int wn    = wave & 1;
    const int rb    = blockIdx.x >> 3;
    const int split = blockIdx.x & 7;
    const int qbase = rb * QTILE;
    const int l31   = lane & 31;
    const int l5    = lane >> 5;

    int  laneoff[6];
    int  ldsoff[6];
    bool isA[6];
#pragma unroll
    for (int c = 0; c < 6; ++c) {
        const int G = wave * 6 + c;
        const bool a = (G < 16);
        const int idx = a ? G : (G - 16);
        const int row = (idx >> 1) * 32 + l31;
        const int oct = (idx & 1) * 2 + l5;
        laneoff[c] = row * EMB + oct * 8;
        ldsoff[c]  = idx * 512;
        isA[c]     = a;
    }
    const int qoff = qbase * EMB;

    auto stage = [&](int cand0, int kk, int buf) {
#pragma unroll
        for (int c = 0; c < 6; ++c) {
            const int goff = laneoff[c] + kk + (isA[c] ? cand0 * EMB : qoff);
            ushort_t* lp = isA[c] ? (sh.s.A[buf] + ldsoff[c]) : (sh.s.B[buf] + ldsoff[c]);
            GLOAD_LDS(Xbf + goff, lp);
        }
    };

    uint32 tv[2][LDEPTH];
#pragma unroll
    for (int fc = 0; fc < 2; ++fc)
#pragma unroll
        for (int s = 0; s < LDEPTH; ++s) tv[fc][s] = 0u;

    f32x16 acc[4][2];
#pragma unroll
    for (int fr = 0; fr < 4; ++fr)
#pragma unroll
        for (int fc = 0; fc < 2; ++fc)
#pragma unroll
            for (int q = 0; q < 16; ++q) acc[fr][fc][q] = 0.f;

    stage(split * CPS + 0 * CTILE, 0, 0);

#pragma unroll 1
    for (int s = 0; s < NSTEPS; ++s) {
        const int ct   = s >> 4;
        const int buf  = s & 1;
        const int cand0 = split * CPS + ct * CTILE;

        __syncthreads();

        if (s + 1 < NSTEPS) {
            const int s2 = s + 1;
            stage(split * CPS + (s2 >> 4) * CTILE, (s2 & 15) * KSLAB, s2 & 1);
        }

        bf16x8 aH[4][2], bH[2][2];
#pragma unroll
        for (int fr = 0; fr < 4; ++fr)
#pragma unroll
            for (int kt = 0; kt < 2; ++kt)
                aH[fr][kt] = *(const bf16x8*)&sh.s.A[buf][((wm * 4 + fr) * 128 + kt * 64 + lane) * 8];
#pragma unroll
        for (int fc = 0; fc < 2; ++fc)
#pragma unroll
            for (int kt = 0; kt < 2; ++kt)
                bH[fc][kt] = *(const bf16x8*)&sh.s.B[buf][((wn * 2 + fc) * 128 + kt * 64 + lane) * 8];

#pragma unroll
        for (int kt = 0; kt < 2; ++kt)
#pragma unroll
            for (int fr = 0; fr < 4; ++fr)
#pragma unroll
                for (int fc = 0; fc < 2; ++fc)
                    acc[fr][fc] = __builtin_amdgcn_mfma_f32_32x32x16_bf16(
                        aH[fr][kt], bH[fc][kt], acc[fr][fc], 0, 0, 0);

        if ((s & 15) == 15) {
#pragma unroll
            for (int fc = 0; fc < 2; ++fc) {
#pragma unroll
                for (int fr = 0; fr < 4; ++fr) {
                    float m0 = fmaxf(fmaxf(acc[fr][fc][0],  acc[fr][fc][1]),  fmaxf(acc[fr][fc][2],  acc[fr][fc][3]));
                    float m1 = fmaxf(fmaxf(acc[fr][fc][4],  acc[fr][fc][5]),  fmaxf(acc[fr][fc][6],  acc[fr][fc][7]));
                    float m2 = fmaxf(fmaxf(acc[fr][fc][8],  acc[fr][fc][9]),  fmaxf(acc[fr][fc][10], acc[fr][fc][11]));
                    float m3 = fmaxf(fmaxf(acc[fr][fc][12], acc[fr][fc][13]), fmaxf(acc[fr][fc][14], acc[fr][fc][15]));
                    float mx = fmaxf(fmaxf(m0, m1), fmaxf(m2, m3));
                    if (packkey(mx, 0) > tv[fc][LDEPTH - 1]) {
                        const int jb = cand0 + wm * 128 + fr * 32 + (l5 << 2);
#pragma unroll
                        for (int reg = 0; reg < 16; ++reg) {
                            const int ci = jb + (reg & 3) + ((reg >> 2) << 3);
                            uint32 key = packkey(acc[fr][fc][reg], ci);
                            if (key > tv[fc][LDEPTH - 1]) {
                                uint32 cur = key;
#pragma unroll
                                for (int d = 0; d < LDEPTH; ++d) {
                                    uint32 a  = tv[fc][d];
                                    bool   gt = cur > a;
                                    tv[fc][d] = gt ? cur : a;
                                    cur       = gt ? a : cur;
                                }
                            }
                        }
                    }
#pragma unroll
                    for (int q = 0; q < 16; ++q) acc[fr][fc][q] = 0.f;
                }
            }
        }
    }

    __syncthreads();
#pragma unroll
    for (int fc = 0; fc < 2; ++fc) {
        const int col = wn * 64 + fc * 32 + l31;
        const int sl  = wm * 2 + l5;
#pragma unroll
        for (int d = 0; d < LDEPTH; ++d) sh.m.mk[col][sl * 16 + d] = tv[fc][d];
#pragma unroll
        for (int d = LDEPTH; d < 16; ++d) sh.m.mk[col][sl * 16 + d] = 0u;
    }
    __syncthreads();
    if (t < 128) {
        int p[4] = {0, 0, 0, 0};
        const size_t base = ((size_t)(qbase + t) * NSPLIT + split) * KEEP;
#pragma unroll 1
        for (int sel = 0; sel < KEEP; ++sel) {
            uint32 bk = 0; int bl = 0;
#pragma unroll
            for (int l = 0; l < 4; ++l) {
                uint32 k = sh.m.mk[t][l * 16 + p[l]];
                if (k > bk) { bk = k; bl = l; }
            }
            p[bl]++;
            keys_out[base + sel] = bk;
        }
    }
}

// ---------------- Phase C: rank-select merge + fp64 exact rescue + output ----------------
__global__ __launch_bounds__(256) void rescue_kernel(
    const float* __restrict__ E, const double* __restrict__ invd,
    const uint32* __restrict__ keys,
    const int* __restrict__ n_users, const int* __restrict__ n_entitys,
    const int* __restrict__ interactions, float* __restrict__ out) {

    __shared__ uint32 fk[4][NSPLIT * KEEP];   // 4 rows x 128 keys
    __shared__ int    scand[4][16];
    __shared__ double dsim[4][16];
    __shared__ int    dcand[4][16];
    __shared__ float  dmemb[4][16];

    const int t    = threadIdx.x;
    const int lane = t & 63;
    const int w    = t >> 6;
    const int row0 = blockIdx.x * 4;
    const int row  = row0 + w;

    {
        uint32* flat = &fk[0][0];
        flat[t]       = keys[(size_t)row0 * 128 + t];
        flat[t + 256] = keys[(size_t)row0 * 128 + t + 256];
    }
    if (lane < 16) scand[w][lane] = 0;     // robustness: no slot is ever garbage
    __syncthreads();

    const int ent = n_entitys[row];

    // parallel rank-select; slot-index tie-break makes ranks unique even under
    // (pathological) duplicate keys, so scand[0..15] is always fully written
    {
        const uint32 k0 = fk[w][lane], k1 = fk[w][lane + 64];
        int r0 = 0, r1 = 0;
#pragma unroll 8
        for (int j = 0; j < 128; ++j) {
            const uint32 kb = fk[w][j];     // wave-broadcast LDS read
            r0 += (kb > k0) || (kb == k0 && j < lane);
            r1 += (kb > k1) || (kb == k1 && j < lane + 64);
        }
        if (r0 < 16) scand[w][r0] = (int)((k0 & 0x1FFFu) ^ 0x1FFFu);
        if (r1 < 16) scand[w][r1] = (int)((k1 & 0x1FFFu) ^ 0x1FFFu);
    }
    __syncthreads();

    const int g = lane >> 2;       // candidate slot 0..15
    const int r = lane & 3;        // K sub-chunk
    const int mycand = scand[w][g] & (NROWS - 1);   // always in-bounds

    // fp64 exact dot; float4 index j*4+r => group's 4 lanes cover ONE 64B line/instr
    const float4* Q = (const float4*)(E + (size_t)row    * EMB);
    const float4* C = (const float4*)(E + (size_t)mycand * EMB);
    double acc = 0.0;
#pragma unroll 8
    for (int j = 0; j < 32; ++j) {
        float4 q = Q[j * 4 + r];
        float4 c = C[j * 4 + r];
        acc += (double)q.x * c.x + (double)q.y * c.y
             + (double)q.z * c.z + (double)q.w * c.w;
    }
    acc += __shfl_xor(acc, 1);
    acc += __shfl_xor(acc, 2);
    if (r == 0) {
        dsim[w][g]  = acc * invd[row] * invd[mycand];
        dcand[w][g] = mycand;
    }
    if (r == 1) {   // parallel membership gather: 16 in flight per wave
        const int uid = n_users[mycand];
        dmemb[w][g] = (float)interactions[(size_t)uid * NITEMS + ent];
    }
    __syncthreads();

    if (lane == 0) {
        unsigned used = 0;
        double sum = 0.0;
#pragma unroll 1
        for (int sel = 0; sel < 6; ++sel) {
            double bv = -1e300; int bi = 0x7FFFFFFF; int bg = 0;
#pragma unroll
            for (int i = 0; i < 16; ++i) {
                if (!((used >> i) & 1u)) {
                    double v = dsim[w][i]; int id = dcand[w][i];
                    if (v > bv || (v == bv && id < bi)) { bv = v; bi = id; bg = i; }
                }
            }
            used |= 1u << bg;
            sum += bv * (double)dmemb[w][bg];
        }
        out[row] = (float)(sum * (1.0 / 6.0));
    }
}

extern "C" void kernel_launch(void* const* d_in, const int* in_sizes, int n_in,
                              void* d_out, int out_size, void* d_ws, size_t ws_size,
                              hipStream_t stream) {
    const float* E            = (const float*)d_in[0];
    const int*   n_users      = (const int*)d_in[1];
    const int*   n_entitys    = (const int*)d_in[2];
    const int*   interactions = (const int*)d_in[3];
    float*       out          = (float*)d_out;

    ushort_t* Xbf  = (ushort_t*)d_ws;
    double*   invd = (double*)(Xbf + (size_t)NROWS * EMB);
    uint32*   keys = (uint32*)(invd + NROWS);

    prep_kernel<<<NROWS / 4, 256, 0, stream>>>(E, Xbf, invd);
    sim_topk_mfma<<<(NROWS / QTILE) * NSPLIT, 256, 0, stream>>>(Xbf, keys);
    rescue_kernel<<<NROWS / 4, 256, 0, stream>>>(E, invd, keys, n_users, n_entitys,
                                                 interactions, out);
}